// Round 12
// baseline (168.209 us; speedup 1.0000x reference)
//
#include <hip/hip_runtime.h>
#include <math.h>

#define EPSBN 1e-5f
#define AADD(p, v) __hip_atomic_fetch_add((p), (v), __ATOMIC_RELAXED, __HIP_MEMORY_SCOPE_AGENT)

typedef unsigned short u16;
typedef short bf16x8 __attribute__((ext_vector_type(8)));
typedef float f32x4 __attribute__((ext_vector_type(4)));
typedef float f32x16 __attribute__((ext_vector_type(16)));

constexpr int NROWS = 8192;
constexpr int NCLS = 10;
constexpr int MPAD = 8832;        // 138 tiles of 64
constexpr int NT_PAD = 138;
constexpr int GY = 16;
constexpr float SCL  = 2.0813689810056077f;   // (log2 e)^2
constexpr float SCL2 = -4.1627379620112154f;  // -2*(log2 e)^2

// workspace offsets (floats)
constexpr size_t OFF_W0P = 0;                      // u16[65536]
constexpr size_t OFF_H1H = 32768;                  // u16[16384*128] = 1048576 f
constexpr size_t OFF_H1L = OFF_H1H + 1048576;
constexpr size_t OFF_SUM = OFF_H1L + 1048576;      // 768 f (zeroed in k_prep)
constexpr size_t OFF_H2  = OFF_SUM + 768;          // 16384*64 f
constexpr size_t OFF_PIDX = OFF_H2 + 1048576;      // int[8832]
constexpr size_t OFF_TCLS = OFF_PIDX + MPAD;       // int[144]
constexpr size_t OFF_PART = OFF_TCLS + 144;        // 16*11*8192 = 1441792 f (dedicated)
// overlays over h1 (dead after layer2)
constexpr size_t OFF_QB  = OFF_H1H;                // u16[8192*64]  = 262144 f
constexpr size_t OFF_KB  = OFF_QB + 262144;        // u16[8832*64]  = 282624 f
constexpr size_t OFF_QN2 = OFF_KB + 282624;        // 8192 f
constexpr size_t OFF_KN2 = OFF_QN2 + NROWS;        // 8832 f

__device__ inline u16 f2bf(float f) {
  unsigned u = __float_as_uint(f);
  unsigned r = (u + 0x7fffu + ((u >> 16) & 1u)) >> 16;
  return (u16)r;
}
__device__ inline float bf2f(u16 h) { return __uint_as_float(((unsigned)h) << 16); }

__device__ inline float tanh_fast(float x) {
  float e = __builtin_amdgcn_exp2f(x * 2.88539008f);
  return 1.f - 2.f * __builtin_amdgcn_rcpf(e + 1.f);
}

__device__ inline void glds16(const u16* g, u16* l) {
  __builtin_amdgcn_global_load_lds(
      (const __attribute__((address_space(1))) unsigned int*)g,
      (__attribute__((address_space(3))) unsigned int*)l, 16, 0, 0);
}

// ---------------- prep: W0 pack (0-127) | aux (128) | per-class scatter (129-138) --
__global__ __launch_bounds__(256) void k_prep(
    const float* __restrict__ w0, const int* __restrict__ yn,
    u16* __restrict__ w0p, int* __restrict__ pidx, int* __restrict__ tcls,
    float* __restrict__ sums)
{
  const int B = blockIdx.x;
  const int tid = threadIdx.x;
  if (B < 128) {
    int idx = B * 256 + tid;
    int t = idx & 255;
    float v = w0[idx];
    u16 hi = f2bf(v);
    u16 lo = f2bf(v - bf2f(hi));
    int j = idx >> 8;
    w0p[(t >> 3) * 1024 + j * 8 + (t & 7)] = hi;
    w0p[32768 + (t >> 3) * 1024 + j * 8 + (t & 7)] = lo;
    return;
  }

  __shared__ int cnt[256][NCLS];
  __shared__ int counts[NCLS];
  __shared__ int pst[NCLS + 1];
  const int lane = tid & 63, wv = tid >> 6;
  #pragma unroll
  for (int c = 0; c < NCLS; ++c) cnt[tid][c] = 0;
  __syncthreads();
  for (int i = tid; i < NROWS; i += 256) cnt[tid][yn[i]]++;
  __syncthreads();
  if (tid < NCLS) {
    int s = 0;
    for (int t = 0; t < 256; ++t) s += cnt[t][tid];
    counts[tid] = s;
  }
  __syncthreads();
  if (tid == 0) {
    int run = 0;
    #pragma unroll
    for (int c = 0; c < NCLS; ++c) {
      pst[c] = run;
      run += ((counts[c] + 63) >> 6) << 6;
    }
    pst[NCLS] = run;
  }
  __syncthreads();

  if (B == 128) {
    sums[tid] = 0.f; sums[tid + 256] = 0.f; sums[tid + 512] = 0.f;
    if (tid == 0) {
      #pragma unroll
      for (int c = 0; c < NCLS; ++c) {
        int nt = (counts[c] + 63) >> 6;
        for (int tt = 0; tt < nt; ++tt) tcls[(pst[c] >> 6) + tt] = c;
      }
      for (int tt = pst[NCLS] >> 6; tt < NT_PAD; ++tt) tcls[tt] = NCLS;
    }
    for (int i = tid; i < MPAD; i += 256) {
      bool pad;
      if (i >= pst[NCLS]) pad = true;
      else {
        int c = 0;
        while (i >= pst[c + 1]) ++c;
        pad = (i >= pst[c] + counts[c]);
      }
      if (pad) pidx[i] = -1;
    }
    return;
  }

  const int c = B - 129;
  __shared__ int wsum[4];
  int x = cnt[tid][c];
  int inc = x;
  #pragma unroll
  for (int d = 1; d < 64; d <<= 1) { int y = __shfl_up(inc, d); if (lane >= d) inc += y; }
  if (lane == 63) wsum[wv] = inc;
  __syncthreads();
  int add = 0;
  for (int w2 = 0; w2 < 4; ++w2) if (w2 < wv) add += wsum[w2];
  int base = pst[c] + (inc - x) + add;
  for (int i = tid; i < NROWS; i += 256) {
    if (yn[i] == c) pidx[base++] = i;
  }
}

// ---------------- layer 1 (3-pass MFMA, relaxed atomic BN stats only) -----------
__global__ __launch_bounds__(256) void k_layer1(
    const float* __restrict__ x, const float* __restrict__ xn,
    const u16* __restrict__ w0p, const float* __restrict__ b0,
    u16* __restrict__ h1h, u16* __restrict__ h1l, float* __restrict__ sums)
{
  const int tid = threadIdx.x;
  const int w = tid >> 6, l = tid & 63;
  const int l15 = l & 15, l4 = l >> 4;
  const int blk = blockIdx.x;                 // 512
  const int rowHalf = w & 1, colHalf = w >> 1;
  const int r0 = blk * 32 + 16 * rowHalf;
  const int c0 = 64 * colHalf;
  const int b = (blk < 256) ? 0 : 1;
  const float* src = (blk < 256) ? (x + (size_t)blk * 32 * 256)
                                 : (xn + (size_t)(blk - 256) * 32 * 256);
  const float* xrow = src + (size_t)(16 * rowHalf + l15) * 256;

  f32x4 acc[4];
  #pragma unroll
  for (int ct = 0; ct < 4; ++ct) acc[ct] = (f32x4){0.f, 0.f, 0.f, 0.f};

  #pragma unroll
  for (int ks = 0; ks < 8; ++ks) {
    const float* xp = xrow + ks * 32 + l4 * 8;
    f32x4 a0 = *(const f32x4*)xp;
    f32x4 a1 = *(const f32x4*)(xp + 4);
    bf16x8 ah, al_;
    #pragma unroll
    for (int i = 0; i < 4; ++i) {
      u16 h = f2bf(a0[i]); ah[i] = (short)h; al_[i] = (short)f2bf(a0[i] - bf2f(h));
    }
    #pragma unroll
    for (int i = 0; i < 4; ++i) {
      u16 h = f2bf(a1[i]); ah[4 + i] = (short)h; al_[4 + i] = (short)f2bf(a1[i] - bf2f(h));
    }
    const u16* bbase = w0p + (size_t)(ks * 4 + l4) * 1024;
    #pragma unroll
    for (int ct = 0; ct < 4; ++ct) {
      const int col = c0 + 16 * ct + l15;
      bf16x8 bh = *(const bf16x8*)(bbase + col * 8);
      bf16x8 bl = *(const bf16x8*)(bbase + 32768 + col * 8);
      acc[ct] = __builtin_amdgcn_mfma_f32_16x16x32_bf16(ah, bh, acc[ct], 0, 0, 0);
      acc[ct] = __builtin_amdgcn_mfma_f32_16x16x32_bf16(ah, bl, acc[ct], 0, 0, 0);
      acc[ct] = __builtin_amdgcn_mfma_f32_16x16x32_bf16(al_, bh, acc[ct], 0, 0, 0);
    }
  }

  #pragma unroll
  for (int ct = 0; ct < 4; ++ct) {
    const int col = c0 + 16 * ct + l15;
    const float bj = b0[col];
    float s = 0.f, q = 0.f;
    #pragma unroll
    for (int r = 0; r < 4; ++r) {
      float v = tanh_fast(acc[ct][r] + bj);
      const int row = r0 + 4 * l4 + r;
      u16 hi = f2bf(v);
      h1h[(size_t)row * 128 + col] = hi;
      h1l[(size_t)row * 128 + col] = f2bf(v - bf2f(hi));
      s += v; q += v * v;
    }
    s += __shfl_xor(s, 16); s += __shfl_xor(s, 32);
    q += __shfl_xor(q, 16); q += __shfl_xor(q, 32);
    if (l < 16) {
      AADD(&sums[b * 128 + col], s);
      AADD(&sums[256 + b * 128 + col], q);
    }
  }
}

// ---------- layer 2 with per-block BN1-fold in LDS (replaces k_foldp launch) -----
// Kernel boundary after layer1 orders the stats; fold is recomputed per block
// (R7-P2-verified code path). No acq/rel atomics anywhere.
__global__ __launch_bounds__(256) void k_layer2(
    const u16* __restrict__ h1h, const u16* __restrict__ h1l,
    const float* __restrict__ W1, const float* __restrict__ b1,
    const float* __restrict__ g0, const float* __restrict__ bt0,
    float* __restrict__ h2, float* __restrict__ sums)
{
  __shared__ u16 w1l[16384];          // 32 KB: hi [0..8191], lo [8192..16383]
  __shared__ float sc0s[128], sh0s[128], b1es[64];
  const int tid = threadIdx.x;
  const int w = tid >> 6, l = tid & 63;
  const int l15 = l & 15, l4 = l >> 4;
  const int blk = blockIdx.x;
  const int rowHalf = w & 1, colHalf = w >> 1;
  const int r0 = blk * 32 + 16 * rowHalf;
  const int c0 = 32 * colHalf;
  const int b = blk >> 8;

  if (tid < 128) {
    float s = sums[b * 128 + tid], q = sums[256 + b * 128 + tid];
    float m = s * (1.f / 8192.f);
    float v = q * (1.f / 8192.f) - m * m;
    float sc = g0[tid] * rsqrtf(v + EPSBN);
    sc0s[tid] = sc;
    sh0s[tid] = bt0[tid] - m * sc;
  }
  __syncthreads();
  for (int e = tid; e < 8192; e += 256) {
    const int j = e >> 6, o = e & 63;
    float wv = W1[o * 128 + j];
    float wsc = wv * sc0s[j];
    u16 hi = f2bf(wsc);
    w1l[(j >> 3) * 512 + o * 8 + (j & 7)] = hi;
    w1l[8192 + (j >> 3) * 512 + o * 8 + (j & 7)] = f2bf(wsc - bf2f(hi));
  }
  if (tid < 64) {
    float a = 0.f;
    for (int j = 0; j < 128; ++j) a = fmaf(W1[tid * 128 + j], sh0s[j], a);
    b1es[tid] = b1[tid] + a;
  }
  __syncthreads();

  const u16* arow_h = h1h + (size_t)(r0 + l15) * 128;
  const u16* arow_l = h1l + (size_t)(r0 + l15) * 128;

  f32x4 acc[2];
  acc[0] = (f32x4){0.f, 0.f, 0.f, 0.f};
  acc[1] = (f32x4){0.f, 0.f, 0.f, 0.f};

  #pragma unroll
  for (int ks = 0; ks < 4; ++ks) {
    bf16x8 ah = *(const bf16x8*)(arow_h + ks * 32 + l4 * 8);
    bf16x8 al_ = *(const bf16x8*)(arow_l + ks * 32 + l4 * 8);
    const u16* bb = w1l + (size_t)(ks * 4 + l4) * 512;
    #pragma unroll
    for (int ct = 0; ct < 2; ++ct) {
      const int col = c0 + 16 * ct + l15;
      bf16x8 bh = *(const bf16x8*)(bb + col * 8);
      bf16x8 bl = *(const bf16x8*)(bb + 8192 + col * 8);
      acc[ct] = __builtin_amdgcn_mfma_f32_16x16x32_bf16(ah, bh, acc[ct], 0, 0, 0);
      acc[ct] = __builtin_amdgcn_mfma_f32_16x16x32_bf16(ah, bl, acc[ct], 0, 0, 0);
      acc[ct] = __builtin_amdgcn_mfma_f32_16x16x32_bf16(al_, bh, acc[ct], 0, 0, 0);
    }
  }

  #pragma unroll
  for (int ct = 0; ct < 2; ++ct) {
    const int col = c0 + 16 * ct + l15;
    const float bj = b1es[col];
    float s = 0.f, q = 0.f;
    #pragma unroll
    for (int r = 0; r < 4; ++r) {
      float v = tanh_fast(acc[ct][r] + bj);
      const int row = r0 + 4 * l4 + r;
      h2[(size_t)row * 64 + col] = v;
      s += v; q += v * v;
    }
    s += __shfl_xor(s, 16); s += __shfl_xor(s, 32);
    q += __shfl_xor(q, 16); q += __shfl_xor(q, 32);
    if (l < 16) {
      AADD(&sums[512 + b * 64 + col], s);
      AADD(&sums[640 + b * 64 + col], q);
    }
  }
}

// ---------------- BN2 + single-bf16 round (q + permuted/padded k) ----------------
__global__ __launch_bounds__(256) void k_bn2(
    const float* __restrict__ h2, const float* __restrict__ sums,
    const float* __restrict__ g1, const float* __restrict__ bt1,
    const int* __restrict__ pidx,
    u16* __restrict__ qb, float* __restrict__ qn2,
    u16* __restrict__ kb, float* __restrict__ kn2)
{
  const int tid = threadIdx.x;
  const int r = tid >> 6, o = tid & 63;
  const bool isq = (blockIdx.x < 2048);
  const int b = isq ? 0 : 1;
  float s = sums[512 + b * 64 + o], q = sums[640 + b * 64 + o];
  float m = s * (1.f / 8192.f);
  float v = q * (1.f / 8192.f) - m * m;
  float sc = g1[o] * rsqrtf(v + EPSBN);
  float sh = bt1[o] - m * sc;
  if (isq) {
    const int row = blockIdx.x * 4 + r;
    float vv = sc * h2[(size_t)row * 64 + o] + sh;
    qb[(size_t)row * 64 + o] = f2bf(vv);
    float sq = vv * vv;
    #pragma unroll
    for (int off = 32; off; off >>= 1) sq += __shfl_xor(sq, off);
    if (o == 0) qn2[row] = SCL * sq;
  } else {
    const int row = (blockIdx.x - 2048) * 4 + r;   // 0..8831
    const int src = pidx[row];
    float vv = 0.f;
    if (src >= 0) vv = sc * h2[(size_t)(NROWS + src) * 64 + o] + sh;
    kb[(size_t)row * 64 + o] = f2bf(vv);
    float sq = vv * vv;
    #pragma unroll
    for (int off = 32; off; off >>= 1) sq += __shfl_xor(sq, off);
    if (o == 0) kn2[row] = (src >= 0) ? SCL * sq : 1e30f;
  }
}

// -------- cdist: 1-pass bf16, 64-col tiles, TRIPLE buffer + counted vmcnt --------
__global__ __launch_bounds__(256, 4) void k_dist(
    const u16* __restrict__ qb, const float* __restrict__ qn2,
    const u16* __restrict__ kb, const float* __restrict__ kn2,
    const int* __restrict__ tcls, float* __restrict__ part)
{
  __shared__ u16 bs[3][4096];                       // 3 x 8 KB
  __shared__ float cls_lds[2 * (NCLS + 1) * 64];
  const int tid = threadIdx.x;
  const int w = tid >> 6, l = tid & 63;
  const int n0 = blockIdx.x * 64;
  const int g = blockIdx.y;
  const int t0 = (g * NT_PAD) / GY, t1 = ((g + 1) * NT_PAD) / GY;

  for (int i = tid; i < 2 * (NCLS + 1) * 64; i += 256) cls_lds[i] = 0.f;

  const int lh = l >> 5;
  const int rb = w >> 1, ch = w & 1;
  const int arow = n0 + 32 * rb + (l & 31);
  bf16x8 aB[4];
  #pragma unroll
  for (int j = 0; j < 4; ++j)
    aB[j] = *(const bf16x8*)(qb + (size_t)arow * 64 + j * 16 + 8 * lh);
  float qnr[16];
  #pragma unroll
  for (int g4 = 0; g4 < 4; ++g4) {
    f32x4 qv = *(const f32x4*)(qn2 + n0 + 32 * rb + 8 * g4 + 4 * lh);
    qnr[4*g4+0] = qv[0]; qnr[4*g4+1] = qv[1]; qnr[4*g4+2] = qv[2]; qnr[4*g4+3] = qv[3];
  }

  int soff[2];
  #pragma unroll
  for (int q = 0; q < 2; ++q)
    soff[q] = (16 * w + 8 * q + (l >> 3)) * 64 + ((l & 7) ^ (l >> 3)) * 8;   // u16 units

  const int colL = 32 * ch + (l & 31);
  const int c7 = colL & 7;

#define STAGE(TT, PB) do { const u16* gp_ = kb + (size_t)(TT) * 4096; \
    u16* lb_ = &bs[PB][0] + w * 1024; \
    glds16(gp_ + soff[0], lb_); \
    glds16(gp_ + soff[1], lb_ + 512); } while (0)

#define FLUSH(CC) do { \
    _Pragma("unroll") for (int r = 0; r < 16; ++r) { \
      run[r] += __shfl_xor(run[r], 1);  run[r] += __shfl_xor(run[r], 2); \
      run[r] += __shfl_xor(run[r], 4);  run[r] += __shfl_xor(run[r], 8); \
      run[r] += __shfl_xor(run[r], 16); } \
    if ((l & 31) == 0) { \
      float* cl_ = cls_lds + ch * 704 + (CC) * 64 + 32 * rb + 4 * lh; \
      _Pragma("unroll") for (int r = 0; r < 16; ++r) cl_[(r & 3) + 8 * (r >> 2)] += run[r]; } \
    _Pragma("unroll") for (int r = 0; r < 16; ++r) run[r] = 0.f; } while (0)

  STAGE(t0, 0);
  if (t0 + 1 < t1) STAGE(t0 + 1, 1);

  float run[16];
  #pragma unroll
  for (int r = 0; r < 16; ++r) run[r] = 0.f;
  int ccur = tcls[t0];
  int p = 0;

  for (int t = t0; t < t1; ++t) {
    if (t + 1 < t1) { asm volatile("s_waitcnt vmcnt(2)" ::: "memory"); }
    else            { asm volatile("s_waitcnt vmcnt(0)" ::: "memory"); }
    __builtin_amdgcn_s_barrier();
    asm volatile("" ::: "memory");

    if (t + 2 < t1) { int pb2 = p + 2; if (pb2 >= 3) pb2 -= 3; STAGE(t + 2, pb2); }

    const int c = tcls[t];
    if (c != ccur) { FLUSH(ccur); ccur = c; }
    const float kv = kn2[t * 64 + colL];

    f32x16 acc0, acc1;
    #pragma unroll
    for (int r = 0; r < 16; ++r) { acc0[r] = 0.f; acc1[r] = 0.f; }
    const char* pb_ = (const char*)&bs[p][0] + colL * 128;
    {
      bf16x8 b0_ = *(const bf16x8*)(pb_ + (((0 + lh) ^ c7) << 4));
      bf16x8 b1_ = *(const bf16x8*)(pb_ + (((2 + lh) ^ c7) << 4));
      bf16x8 b2_ = *(const bf16x8*)(pb_ + (((4 + lh) ^ c7) << 4));
      bf16x8 b3_ = *(const bf16x8*)(pb_ + (((6 + lh) ^ c7) << 4));
      acc0 = __builtin_amdgcn_mfma_f32_32x32x16_bf16(aB[0], b0_, acc0, 0, 0, 0);
      acc1 = __builtin_amdgcn_mfma_f32_32x32x16_bf16(aB[1], b1_, acc1, 0, 0, 0);
      acc0 = __builtin_amdgcn_mfma_f32_32x32x16_bf16(aB[2], b2_, acc0, 0, 0, 0);
      acc1 = __builtin_amdgcn_mfma_f32_32x32x16_bf16(aB[3], b3_, acc1, 0, 0, 0);
    }
    #pragma unroll
    for (int r = 0; r < 16; ++r) {
      float d2 = fmaf(SCL2, acc0[r] + acc1[r], qnr[r] + kv);
      d2 = fmaxf(d2, 2.0813689e-12f);
      run[r] += __builtin_amdgcn_exp2f(-__builtin_amdgcn_sqrtf(d2));
    }
    p = (p == 2) ? 0 : p + 1;
  }
  FLUSH(ccur);
  __syncthreads();

  for (int i = tid; i < (NCLS + 1) * 64; i += 256) {
    const int c = i >> 6, rr = i & 63;
    part[((size_t)g * (NCLS + 1) + c) * NROWS + n0 + rr] = cls_lds[i] + cls_lds[704 + i];
  }
#undef STAGE
#undef FLUSH
}

// ---- finalize ----
__global__ __launch_bounds__(256) void k_final(const float* __restrict__ part,
                                               float* __restrict__ out)
{
  const int n = blockIdx.x * 256 + threadIdx.x;
  float sc[NCLS];
  #pragma unroll
  for (int c = 0; c < NCLS; ++c) sc[c] = 0.f;
  for (int g = 0; g < GY; ++g) {
    #pragma unroll
    for (int c = 0; c < NCLS; ++c)
      sc[c] += part[((size_t)g * (NCLS + 1) + c) * NROWS + n];
  }
  float tot = 0.f;
  #pragma unroll
  for (int c = 0; c < NCLS; ++c) tot += sc[c];
  const float inv = 1.f / tot;
  #pragma unroll
  for (int c = 0; c < NCLS; ++c)
    out[(size_t)n * NCLS + c] = fminf(fmaxf(sc[c] * inv, 0.f), 1.f);
}

extern "C" void kernel_launch(void* const* d_in, const int* in_sizes, int n_in,
                              void* d_out, int out_size, void* d_ws, size_t ws_size,
                              hipStream_t stream) {
  const float* x   = (const float*)d_in[0];
  const float* xn  = (const float*)d_in[1];
  const int*   yn  = (const int*)d_in[2];
  const float* W0  = (const float*)d_in[3];
  const float* b0  = (const float*)d_in[4];
  const float* g0  = (const float*)d_in[5];
  const float* bt0 = (const float*)d_in[6];
  const float* W1  = (const float*)d_in[7];
  const float* b1  = (const float*)d_in[8];
  const float* g1  = (const float*)d_in[9];
  const float* bt1 = (const float*)d_in[10];
  float* out = (float*)d_out;
  float* ws  = (float*)d_ws;

  u16*   w0pp = (u16*)(ws + OFF_W0P);
  u16*   h1hp = (u16*)(ws + OFF_H1H);
  u16*   h1lp = (u16*)(ws + OFF_H1L);
  float* sumsp= ws + OFF_SUM;
  float* h2p  = ws + OFF_H2;
  int*   pidxp= (int*)(ws + OFF_PIDX);
  int*   tclsp= (int*)(ws + OFF_TCLS);
  float* partp= ws + OFF_PART;
  u16*   qbp  = (u16*)(ws + OFF_QB);
  float* qn2p = ws + OFF_QN2;
  u16*   kbp  = (u16*)(ws + OFF_KB);
  float* kn2p = ws + OFF_KN2;

  k_prep<<<139, 256, 0, stream>>>(W0, yn, w0pp, pidxp, tclsp, sumsp);
  k_layer1<<<512, 256, 0, stream>>>(x, xn, w0pp, b0, h1hp, h1lp, sumsp);
  k_layer2<<<512, 256, 0, stream>>>(h1hp, h1lp, W1, b1, g0, bt0, h2p, sumsp);
  k_bn2<<<2048 + MPAD / 4, 256, 0, stream>>>(h2p, sumsp, g1, bt1, pidxp,
                                             qbp, qn2p, kbp, kn2p);
  k_dist<<<dim3(128, GY), 256, 0, stream>>>(qbp, qn2p, kbp, kn2p, tclsp, partp);
  k_final<<<32, 256, 0, stream>>>(partp, out);
}